// Round 14
// baseline (2071.184 us; speedup 1.0000x reference)
//
#include <hip/hip_runtime.h>
#include <hip/hip_bf16.h>
#include <stdint.h>

using bf16 = __hip_bfloat16;
typedef __attribute__((ext_vector_type(8))) short bf16x8;
typedef __attribute__((ext_vector_type(8))) unsigned short u16x8;
typedef __attribute__((ext_vector_type(16))) float f32x16;

#define B_ROWS 16384
#define D_DIM  1024
#define NLAYER 18

__device__ inline void gload_lds16(const bf16* g, bf16* l) {
    __builtin_amdgcn_global_load_lds(
        (const __attribute__((address_space(1))) void*)g,
        (__attribute__((address_space(3))) void*)l, 16, 0, 0);
}

__device__ inline unsigned short f2bf_bits(float f) {
    bf16 h = __float2bfloat16(f);
    return *reinterpret_cast<unsigned short*>(&h);
}
__device__ inline float bfbits2f(unsigned short u) {
    unsigned int x = ((unsigned int)u) << 16;
    return __uint_as_float(x);
}
// double-bf16 split: v ~= hi + lo with rel err ~2^-18
__device__ inline void split_bf(float v, unsigned short& hi, unsigned short& lo) {
    hi = f2bf_bits(v);
    float hf = bfbits2f(hi);
    lo = f2bf_bits(v - hf);
}

// ---------------------------------------------------------------------------
// Weff[l][o][i] = (wq-8)*scale + sum_r lora_b[l][o][r]*lora_a[l][r][i]
// stored as hi/lo bf16 pair. One block per (l, 8-row group) (proven r7).
// ---------------------------------------------------------------------------
__global__ __launch_bounds__(256)
void build_weff(const int* __restrict__ wq, const float* __restrict__ scales,
                const float* __restrict__ lora_a, const float* __restrict__ lora_b,
                bf16* __restrict__ weff_h, bf16* __restrict__ weff_l)
{
    const int bb = blockIdx.x;           // 18 * 128
    const int l  = bb >> 7;
    const int o0 = (bb & 127) * 8;
    __shared__ float bsh[8][32];
    {
        const int oo = threadIdx.x >> 5, rr = threadIdx.x & 31;
        bsh[oo][rr] = lora_b[((size_t)l * 1024 + o0 + oo) * 32 + rr];
    }
    __syncthreads();

    const float* abase = lora_a + (size_t)l * 32 * 1024;
    const int i0 = threadIdx.x * 4;      // 256 threads x 4 = 1024 i's
    float acc[8][4] = {};
    #pragma unroll 4
    for (int r = 0; r < 32; ++r) {
        float4 av = *reinterpret_cast<const float4*>(abase + (size_t)r * 1024 + i0);
        #pragma unroll
        for (int o = 0; o < 8; ++o) {
            const float br = bsh[o][r];
            acc[o][0] += br * av.x; acc[o][1] += br * av.y;
            acc[o][2] += br * av.z; acc[o][3] += br * av.w;
        }
    }
    #pragma unroll
    for (int o = 0; o < 8; ++o) {
        const size_t row = (size_t)l * 1024 + o0 + o;
        int4 q = *reinterpret_cast<const int4*>(wq + row * 1024 + i0);
        const float sc = scales[row * 64 + (i0 >> 4)];
        float w0 = (q.x - 8) * sc + acc[o][0];
        float w1 = (q.y - 8) * sc + acc[o][1];
        float w2 = (q.z - 8) * sc + acc[o][2];
        float w3 = (q.w - 8) * sc + acc[o][3];
        ushort4 uh, ul;
        split_bf(w0, uh.x, ul.x); split_bf(w1, uh.y, ul.y);
        split_bf(w2, uh.z, ul.z); split_bf(w3, uh.w, ul.w);
        *reinterpret_cast<ushort4*>(weff_h + row * 1024 + i0) = uh;
        *reinterpret_cast<ushort4*>(weff_l + row * 1024 + i0) = ul;
    }
}

// ---------------------------------------------------------------------------
// x f32 -> hi/lo bf16 pair
// ---------------------------------------------------------------------------
__global__ __launch_bounds__(256)
void cast_split(const float* __restrict__ x, bf16* __restrict__ yh, bf16* __restrict__ yl)
{
    size_t i = ((size_t)blockIdx.x * 256 + threadIdx.x) * 4;
    float4 v = *reinterpret_cast<const float4*>(x + i);
    ushort4 uh, ul;
    split_bf(v.x, uh.x, ul.x); split_bf(v.y, uh.y, ul.y);
    split_bf(v.z, uh.z, ul.z); split_bf(v.w, uh.w, ul.w);
    *reinterpret_cast<ushort4*>(yh + i) = uh;
    *reinterpret_cast<ushort4*>(yl + i) = ul;
}

// ---------------------------------------------------------------------------
// GEMM, double-bf16 operands, 3 MFMA products: acc += Ah*Wh + Ah*Wl + Al*Wh
// 256x256 tile, 8 waves (2M x 4N, per-wave 128x64), 32x32x16 MFMA.
// m201-class 8-phase schedule: K split into 64 half-tiles of K=16; FOUR
// 32 KiB half-buffers (Ah|Al|Wh|Wl, rows of 16 elems); staged 3 ahead with
// COUNTED vmcnt (8 steady, 4/0 only at the tail) — loads stay in flight
// across barriers. Per half-tile: one barrier, then a desync'd stream
// {readW+A01; lgkm0; 12 MFMA} {readA23; lgkm0; 12 MFMA}: early waves'
// reads overlap laggard waves' MFMAs. setprio(1) around MFMA clusters.
// MFMA emission product-major: same-acc spacing 4 (dep-latency slack).
// MODE 0: relu -> pair out;  MODE 1: +res -> pair out;  MODE 2: +res -> f32
// ---------------------------------------------------------------------------
#define HB_E 16384             // elems per half-buffer (4 tensors x 256 x 16)

#define SCHED0 __builtin_amdgcn_sched_barrier(0)

template<int MODE>
__global__ __launch_bounds__(512)
void qgemm3(const bf16* __restrict__ AH, const bf16* __restrict__ AL,
            const bf16* __restrict__ WH, const bf16* __restrict__ WL,
            const float* __restrict__ bias,
            const bf16* __restrict__ RH, const bf16* __restrict__ RL,
            bf16* __restrict__ OH, bf16* __restrict__ OL,
            float* __restrict__ Of)
{
    __shared__ bf16 smem[4 * HB_E];   // 128 KiB (4 half-buffers)

    // T1: chunked XCD swizzle, nwg = 256 (64 m-tiles x 4 n-tiles), 256%8==0.
    const int b  = blockIdx.x;
    const int sb = ((b & 7) << 5) | (b >> 3);
    const int n0 = (sb & 3) * 256;
    const int m0 = (sb >> 2) * 256;

    const int tid  = threadIdx.x;
    const int wave = tid >> 6;
    const int lane = tid & 63;
    const int wr = wave >> 2;          // 0..1  M half (128 rows)
    const int wc = wave & 3;           // 0..3  N strip (64 cols)

    const int l31 = lane & 31;         // fragment row/col (32x32)
    const int khalf = lane >> 5;       // fragment k-half (8-elem unit): 0..1

    f32x16 acc[4][2] = {};             // [mt 32-row][nt 32-col], 128 VGPR

    // staging: per half-tile, wave w loads rows [w*32, w*32+32) x 16 k of all
    // 4 tensors = 4 gload_lds (1 KiB each; dst wave-uniform, lane adds 16B)
    const int srow = lane >> 1;        // row within 32-row chunk
    const int skl  = (lane & 1) * 8;   // k offset within 16
    auto stage = [&](int hb, int h) {
        bf16* base = smem + hb * HB_E + wave * 512;
        const size_t kg = (size_t)h * 16 + skl;
        const int rr = wave * 32 + srow;
        gload_lds16(AH + (size_t)(m0 + rr) * D_DIM + kg, base);
        gload_lds16(AL + (size_t)(m0 + rr) * D_DIM + kg, base + 4096);
        gload_lds16(WH + (size_t)(n0 + rr) * D_DIM + kg, base + 8192);
        gload_lds16(WL + (size_t)(n0 + rr) * D_DIM + kg, base + 12288);
    };

    // ---- prologue: half-tiles 0,1,2 into buffers 0,1,2 (12 loads in flight)
    stage(0, 0);
    stage(1, 1);
    stage(2, 2);

    #pragma unroll 1
    for (int h = 0; h < 64; ++h) {
        // counted vmcnt: wait for half-tile h only; up to 2 stay in flight
        SCHED0;
        if (h < 62)      asm volatile("s_waitcnt vmcnt(8)" ::: "memory");
        else if (h == 62) asm volatile("s_waitcnt vmcnt(4)" ::: "memory");
        else              asm volatile("s_waitcnt vmcnt(0)" ::: "memory");
        SCHED0;
        __builtin_amdgcn_s_barrier();   // h resident everywhere; h-1 reads done
        if (h < 61)
            stage((h + 3) & 3, h + 3);  // overwrites h-1's buffer — safe
        SCHED0;

        const bf16* tb = smem + (h & 3) * HB_E;

        // phase 1: W frags + A quadrants 0,1 (8 ds_read_b128)
        bf16x8 wfh[2], wfl[2], fah[4], fal[4];
        #pragma unroll
        for (int nt = 0; nt < 2; ++nt) {
            int off = (wc * 64 + nt * 32 + l31) * 16 + khalf * 8;
            wfh[nt] = *reinterpret_cast<const bf16x8*>(tb + 8192 + off);
            wfl[nt] = *reinterpret_cast<const bf16x8*>(tb + 12288 + off);
        }
        #pragma unroll
        for (int mt = 0; mt < 2; ++mt) {
            int off = (wr * 128 + mt * 32 + l31) * 16 + khalf * 8;
            fah[mt] = *reinterpret_cast<const bf16x8*>(tb + off);
            fal[mt] = *reinterpret_cast<const bf16x8*>(tb + 4096 + off);
        }
        SCHED0;
        asm volatile("s_waitcnt lgkmcnt(0)" ::: "memory");
        SCHED0;
        __builtin_amdgcn_s_setprio(1);
        #pragma unroll
        for (int mt = 0; mt < 2; ++mt)       // product-major: acc spacing 4
            #pragma unroll
            for (int nt = 0; nt < 2; ++nt)
                acc[mt][nt] = __builtin_amdgcn_mfma_f32_32x32x16_bf16(fah[mt], wfh[nt], acc[mt][nt], 0, 0, 0);
        #pragma unroll
        for (int mt = 0; mt < 2; ++mt)
            #pragma unroll
            for (int nt = 0; nt < 2; ++nt)
                acc[mt][nt] = __builtin_amdgcn_mfma_f32_32x32x16_bf16(fah[mt], wfl[nt], acc[mt][nt], 0, 0, 0);
        #pragma unroll
        for (int mt = 0; mt < 2; ++mt)
            #pragma unroll
            for (int nt = 0; nt < 2; ++nt)
                acc[mt][nt] = __builtin_amdgcn_mfma_f32_32x32x16_bf16(fal[mt], wfh[nt], acc[mt][nt], 0, 0, 0);
        __builtin_amdgcn_s_setprio(0);

        // phase 2: A quadrants 2,3 (4 ds_read_b128) — same buffer, no barrier
        #pragma unroll
        for (int mt = 2; mt < 4; ++mt) {
            int off = (wr * 128 + mt * 32 + l31) * 16 + khalf * 8;
            fah[mt] = *reinterpret_cast<const bf16x8*>(tb + off);
            fal[mt] = *reinterpret_cast<const bf16x8*>(tb + 4096 + off);
        }
        SCHED0;
        asm volatile("s_waitcnt lgkmcnt(0)" ::: "memory");
        SCHED0;
        __builtin_amdgcn_s_setprio(1);
        #pragma unroll
        for (int mt = 2; mt < 4; ++mt)
            #pragma unroll
            for (int nt = 0; nt < 2; ++nt)
                acc[mt][nt] = __builtin_amdgcn_mfma_f32_32x32x16_bf16(fah[mt], wfh[nt], acc[mt][nt], 0, 0, 0);
        #pragma unroll
        for (int mt = 2; mt < 4; ++mt)
            #pragma unroll
            for (int nt = 0; nt < 2; ++nt)
                acc[mt][nt] = __builtin_amdgcn_mfma_f32_32x32x16_bf16(fah[mt], wfl[nt], acc[mt][nt], 0, 0, 0);
        #pragma unroll
        for (int mt = 2; mt < 4; ++mt)
            #pragma unroll
            for (int nt = 0; nt < 2; ++nt)
                acc[mt][nt] = __builtin_amdgcn_mfma_f32_32x32x16_bf16(fal[mt], wfh[nt], acc[mt][nt], 0, 0, 0);
        __builtin_amdgcn_s_setprio(0);
    }

    // protect epilogue LDS-scratch reuse from any wave still reading smem
    SCHED0;
    asm volatile("s_waitcnt lgkmcnt(0)" ::: "memory");
    SCHED0;
    __builtin_amdgcn_s_barrier();

    // ---- Epilogue via LDS transpose, 2 half-passes (per-wave 64x64 f32 =
    // 16 KiB x 8 waves = 128 KiB). Wave-private regions; DS in-order per wave.
    // C/D: col = lane&31, row = (reg&3) + 8*(reg>>2) + 4*(lane>>5).
    float* cwave = reinterpret_cast<float*>(smem) + wave * 4096;
    const int rbase = 4 * khalf;
    const int rloc = lane >> 3;
    const int cloc = (lane & 7) * 8;

    #pragma unroll
    for (int half = 0; half < 2; ++half) {
        #pragma unroll
        for (int nt = 0; nt < 2; ++nt) {
            const float bv = bias[n0 + wc * 64 + nt * 32 + l31];
            const int lcol = nt * 32 + l31;               // local col 0..63
            const int chunk = lcol >> 2;
            #pragma unroll
            for (int mm = 0; mm < 2; ++mm) {
                const int mt = half * 2 + mm;
                #pragma unroll
                for (int reg = 0; reg < 16; ++reg) {
                    const int row32 = (reg & 3) + 8 * (reg >> 2) + rbase;
                    const int lrow = mm * 32 + row32;     // local row 0..63
                    float v = acc[mt][nt][reg] + bv;
                    if (MODE == 0) v = v > 0.f ? v : 0.f;
                    cwave[lrow * 64 + (chunk ^ (lrow & 15)) * 4 + (lcol & 3)] = v;
                }
            }
        }
        SCHED0;
        asm volatile("s_waitcnt lgkmcnt(0)" ::: "memory");
        SCHED0;

        #pragma unroll
        for (int pass = 0; pass < 8; ++pass) {
            const int lrow = pass * 8 + rloc;             // 0..63
            const int grow = m0 + wr * 128 + half * 64 + lrow;
            const size_t gbase = (size_t)grow * D_DIM + (n0 + wc * 64 + cloc);
            const int c0 = cloc >> 2;
            float4 v0 = *reinterpret_cast<const float4*>(&cwave[lrow * 64 + ((c0    ) ^ (lrow & 15)) * 4]);
            float4 v1 = *reinterpret_cast<const float4*>(&cwave[lrow * 64 + ((c0 + 1) ^ (lrow & 15)) * 4]);
            float vv[8] = {v0.x, v0.y, v0.z, v0.w, v1.x, v1.y, v1.z, v1.w};
            if (MODE != 0) {
                u16x8 rh = *reinterpret_cast<const u16x8*>(&RH[gbase]);
                u16x8 rl2 = *reinterpret_cast<const u16x8*>(&RL[gbase]);
                #pragma unroll
                for (int k = 0; k < 8; ++k)
                    vv[k] += bfbits2f(rh[k]) + bfbits2f(rl2[k]);
            }
            if (MODE == 2) {
                *reinterpret_cast<float4*>(&Of[gbase])     = make_float4(vv[0], vv[1], vv[2], vv[3]);
                *reinterpret_cast<float4*>(&Of[gbase + 4]) = make_float4(vv[4], vv[5], vv[6], vv[7]);
            } else {
                u16x8 ho, lo2;
                #pragma unroll
                for (int k = 0; k < 8; ++k) {
                    unsigned short hh, l2;
                    split_bf(vv[k], hh, l2);
                    ho[k] = hh; lo2[k] = l2;
                }
                *reinterpret_cast<u16x8*>(&OH[gbase]) = ho;
                *reinterpret_cast<u16x8*>(&OL[gbase]) = lo2;
            }
        }
        SCHED0;
        asm volatile("s_waitcnt lgkmcnt(0)" ::: "memory");
        SCHED0;
    }
}

// ---------------------------------------------------------------------------
// LayerNorm on hi/lo pair. One block per row, 256 threads x 4 elems.
// ---------------------------------------------------------------------------
__global__ __launch_bounds__(256)
void ln_pair(const bf16* __restrict__ XH, const bf16* __restrict__ XL,
             bf16* __restrict__ YH, bf16* __restrict__ YL,
             const float* __restrict__ gamma, const float* __restrict__ beta)
{
    const int row = blockIdx.x;
    const int tid = threadIdx.x;
    const int lane = tid & 63;
    const int wave = tid >> 6;

    ushort4 uh = reinterpret_cast<const ushort4*>(XH + (size_t)row * D_DIM)[tid];
    ushort4 ul = reinterpret_cast<const ushort4*>(XL + (size_t)row * D_DIM)[tid];
    float v0 = bfbits2f(uh.x) + bfbits2f(ul.x);
    float v1 = bfbits2f(uh.y) + bfbits2f(ul.y);
    float v2 = bfbits2f(uh.z) + bfbits2f(ul.z);
    float v3 = bfbits2f(uh.w) + bfbits2f(ul.w);
    float s  = v0 + v1 + v2 + v3;
    float ss = v0 * v0 + v1 * v1 + v2 * v2 + v3 * v3;
    #pragma unroll
    for (int off = 32; off >= 1; off >>= 1) {
        s  += __shfl_xor(s, off, 64);
        ss += __shfl_xor(ss, off, 64);
    }
    __shared__ float red[8];
    if (lane == 0) { red[wave] = s; red[4 + wave] = ss; }
    __syncthreads();
    float S  = red[0] + red[1] + red[2] + red[3];
    float SS = red[4] + red[5] + red[6] + red[7];
    const float mean = S * (1.0f / D_DIM);
    const float var  = SS * (1.0f / D_DIM) - mean * mean;
    const float inv  = rsqrtf(var + 1e-5f);

    const int c0 = tid * 4;
    float y0 = (v0 - mean) * inv * gamma[c0 + 0] + beta[c0 + 0];
    float y1 = (v1 - mean) * inv * gamma[c0 + 1] + beta[c0 + 1];
    float y2 = (v2 - mean) * inv * gamma[c0 + 2] + beta[c0 + 2];
    float y3 = (v3 - mean) * inv * gamma[c0 + 3] + beta[c0 + 3];
    ushort4 oh, ol;
    split_bf(y0, oh.x, ol.x); split_bf(y1, oh.y, ol.y);
    split_bf(y2, oh.z, ol.z); split_bf(y3, oh.w, ol.w);
    reinterpret_cast<ushort4*>(YH + (size_t)row * D_DIM)[tid] = oh;
    reinterpret_cast<ushort4*>(YL + (size_t)row * D_DIM)[tid] = ol;
}

// ---------------------------------------------------------------------------
extern "C" void kernel_launch(void* const* d_in, const int* in_sizes, int n_in,
                              void* d_out, int out_size, void* d_ws, size_t ws_size,
                              hipStream_t stream)
{
    const float* x      = (const float*)d_in[0];
    const int*   wq     = (const int*)d_in[1];
    const float* scales = (const float*)d_in[2];
    const float* bias   = (const float*)d_in[3];
    const float* lora_a = (const float*)d_in[4];
    const float* lora_b = (const float*)d_in[5];
    const float* ln_g   = (const float*)d_in[6];
    const float* ln_b   = (const float*)d_in[7];
    float* out = (float*)d_out;

    char* ws = (char*)d_ws;
    const size_t W_ELEMS = (size_t)NLAYER * D_DIM * D_DIM;
    const size_t H_ELEMS = (size_t)B_ROWS * D_DIM;
    bf16* WHp = (bf16*)ws;
    bf16* WLp = WHp + W_ELEMS;
    bf16* HAh = WLp + W_ELEMS;
    bf16* HAl = HAh + H_ELEMS;
    bf16* HBh = HAl + H_ELEMS;
    bf16* HBl = HBh + H_ELEMS;
    // third activation pair lives in d_out (dead before final write)
    bf16* HCh = (bf16*)d_out;
    bf16* HCl = HCh + H_ELEMS;

    build_weff<<<dim3(NLAYER * 128), dim3(256), 0, stream>>>(wq, scales, lora_a, lora_b, WHp, WLp);
    cast_split<<<dim3((B_ROWS * D_DIM) / (256 * 4)), dim3(256), 0, stream>>>(x, HAh, HAl);

    dim3 ggrid(256);  // 64 m-tiles x 4 n-tiles, swizzled in-kernel
    for (int j = 0; j < 6; ++j) {
        const int l0 = 3 * j;
        const bf16* WH0 = WHp + (size_t)l0 * D_DIM * D_DIM;
        const bf16* WL0 = WLp + (size_t)l0 * D_DIM * D_DIM;
        const bf16* WH1 = WHp + (size_t)(l0 + 1) * D_DIM * D_DIM;
        const bf16* WL1 = WLp + (size_t)(l0 + 1) * D_DIM * D_DIM;
        const bf16* WH2 = WHp + (size_t)(l0 + 2) * D_DIM * D_DIM;
        const bf16* WL2 = WLp + (size_t)(l0 + 2) * D_DIM * D_DIM;
        const float* b0 = bias + (size_t)l0 * D_DIM;
        const float* b1 = bias + (size_t)(l0 + 1) * D_DIM;
        const float* b2 = bias + (size_t)(l0 + 2) * D_DIM;
        if (j < 5) {
            qgemm3<0><<<ggrid, 512, 0, stream>>>(HAh, HAl, WH0, WL0, b0, nullptr, nullptr, HBh, HBl, nullptr);
            qgemm3<0><<<ggrid, 512, 0, stream>>>(HBh, HBl, WH1, WL1, b1, nullptr, nullptr, HCh, HCl, nullptr);
            qgemm3<1><<<ggrid, 512, 0, stream>>>(HCh, HCl, WH2, WL2, b2, HAh, HAl, HBh, HBl, nullptr);
            ln_pair<<<dim3(B_ROWS), dim3(256), 0, stream>>>(HBh, HBl, HAh, HAl,
                                                            ln_g + (size_t)j * D_DIM, ln_b + (size_t)j * D_DIM);
        } else {
            qgemm3<0><<<ggrid, 512, 0, stream>>>(HAh, HAl, WH0, WL0, b0, nullptr, nullptr, HCh, HCl, nullptr);
            qgemm3<0><<<ggrid, 512, 0, stream>>>(HCh, HCl, WH1, WL1, b1, nullptr, nullptr, HBh, HBl, nullptr);
            qgemm3<2><<<ggrid, 512, 0, stream>>>(HBh, HBl, WH2, WL2, b2, HAh, HAl, nullptr, nullptr, out);
        }
    }
}

// Round 16
// 1760.870 us; speedup vs baseline: 1.1762x; 1.1762x over previous
//
#include <hip/hip_runtime.h>
#include <hip/hip_bf16.h>
#include <stdint.h>

using bf16 = __hip_bfloat16;
typedef __attribute__((ext_vector_type(8))) short bf16x8;
typedef __attribute__((ext_vector_type(8))) unsigned short u16x8;
typedef __attribute__((ext_vector_type(4))) float f32x4;

#define B_ROWS 16384
#define D_DIM  1024
#define NLAYER 18

__device__ inline void gload_lds16(const bf16* g, bf16* l) {
    __builtin_amdgcn_global_load_lds(
        (const __attribute__((address_space(1))) void*)g,
        (__attribute__((address_space(3))) void*)l, 16, 0, 0);
}

__device__ inline unsigned short f2bf_bits(float f) {
    bf16 h = __float2bfloat16(f);
    return *reinterpret_cast<unsigned short*>(&h);
}
__device__ inline float bfbits2f(unsigned short u) {
    unsigned int x = ((unsigned int)u) << 16;
    return __uint_as_float(x);
}
// double-bf16 split: v ~= hi + lo with rel err ~2^-18
__device__ inline void split_bf(float v, unsigned short& hi, unsigned short& lo) {
    hi = f2bf_bits(v);
    float hf = bfbits2f(hi);
    lo = f2bf_bits(v - hf);
}

// ---------------------------------------------------------------------------
// Weff[l][o][i] = (wq-8)*scale + sum_r lora_b[l][o][r]*lora_a[l][r][i]
// stored as hi/lo bf16 pair. One block per (l, 8-row group) (proven r7).
// ---------------------------------------------------------------------------
__global__ __launch_bounds__(256)
void build_weff(const int* __restrict__ wq, const float* __restrict__ scales,
                const float* __restrict__ lora_a, const float* __restrict__ lora_b,
                bf16* __restrict__ weff_h, bf16* __restrict__ weff_l)
{
    const int bb = blockIdx.x;           // 18 * 128
    const int l  = bb >> 7;
    const int o0 = (bb & 127) * 8;
    __shared__ float bsh[8][32];
    {
        const int oo = threadIdx.x >> 5, rr = threadIdx.x & 31;
        bsh[oo][rr] = lora_b[((size_t)l * 1024 + o0 + oo) * 32 + rr];
    }
    __syncthreads();

    const float* abase = lora_a + (size_t)l * 32 * 1024;
    const int i0 = threadIdx.x * 4;      // 256 threads x 4 = 1024 i's
    float acc[8][4] = {};
    #pragma unroll 4
    for (int r = 0; r < 32; ++r) {
        float4 av = *reinterpret_cast<const float4*>(abase + (size_t)r * 1024 + i0);
        #pragma unroll
        for (int o = 0; o < 8; ++o) {
            const float br = bsh[o][r];
            acc[o][0] += br * av.x; acc[o][1] += br * av.y;
            acc[o][2] += br * av.z; acc[o][3] += br * av.w;
        }
    }
    #pragma unroll
    for (int o = 0; o < 8; ++o) {
        const size_t row = (size_t)l * 1024 + o0 + o;
        int4 q = *reinterpret_cast<const int4*>(wq + row * 1024 + i0);
        const float sc = scales[row * 64 + (i0 >> 4)];
        float w0 = (q.x - 8) * sc + acc[o][0];
        float w1 = (q.y - 8) * sc + acc[o][1];
        float w2 = (q.z - 8) * sc + acc[o][2];
        float w3 = (q.w - 8) * sc + acc[o][3];
        ushort4 uh, ul;
        split_bf(w0, uh.x, ul.x); split_bf(w1, uh.y, ul.y);
        split_bf(w2, uh.z, ul.z); split_bf(w3, uh.w, ul.w);
        *reinterpret_cast<ushort4*>(weff_h + row * 1024 + i0) = uh;
        *reinterpret_cast<ushort4*>(weff_l + row * 1024 + i0) = ul;
    }
}

// ---------------------------------------------------------------------------
// x f32 -> hi/lo bf16 pair
// ---------------------------------------------------------------------------
__global__ __launch_bounds__(256)
void cast_split(const float* __restrict__ x, bf16* __restrict__ yh, bf16* __restrict__ yl)
{
    size_t i = ((size_t)blockIdx.x * 256 + threadIdx.x) * 4;
    float4 v = *reinterpret_cast<const float4*>(x + i);
    ushort4 uh, ul;
    split_bf(v.x, uh.x, ul.x); split_bf(v.y, uh.y, ul.y);
    split_bf(v.z, uh.z, ul.z); split_bf(v.w, uh.w, ul.w);
    *reinterpret_cast<ushort4*>(yh + i) = uh;
    *reinterpret_cast<ushort4*>(yl + i) = ul;
}

// ---------------------------------------------------------------------------
// GEMM, double-bf16 operands, 3 MFMA products: acc += Ah*Wh + Ah*Wl + Al*Wh
// 256x256 tile, BK=32, 8 waves (2M x 4N, per-wave 128x64).
// Defer-stage schedule (r10, best measured): ONE barrier per K-step:
//   vmcnt(0); bar; stage(kt+1 -> other buf); {24 ds_read || 96 MFMA}
// stage(kt+1) overwrites the buffer read at kt-1 — safe because barrier
// arrival implies each wave's reads(kt-1) were consumed by its MFMAs.
// Post-loop lgkm(0)+barrier protects the epilogue LDS-scratch reuse.
// MODE 0: relu -> pair out;  MODE 1: +res -> pair out;  MODE 2: +res -> f32
// ---------------------------------------------------------------------------
#define TILE_E 8192            // elems per LDS tensor tile (256 rows x 32)
#define SET_E  (4 * TILE_E)    // Ah, Al, Wh, Wl

#define SCHED0 __builtin_amdgcn_sched_barrier(0)

template<int MODE>
__global__ __launch_bounds__(512)
void qgemm3(const bf16* __restrict__ AH, const bf16* __restrict__ AL,
            const bf16* __restrict__ WH, const bf16* __restrict__ WL,
            const float* __restrict__ bias,
            const bf16* __restrict__ RH, const bf16* __restrict__ RL,
            bf16* __restrict__ OH, bf16* __restrict__ OL,
            float* __restrict__ Of)
{
    __shared__ bf16 smem[2 * SET_E];   // 128 KiB

    // T1: chunked XCD swizzle, nwg = 256 (64 m-tiles x 4 n-tiles), 256%8==0.
    const int b  = blockIdx.x;
    const int sb = ((b & 7) << 5) | (b >> 3);
    const int n0 = (sb & 3) * 256;
    const int m0 = (sb >> 2) * 256;

    const int tid  = threadIdx.x;
    const int wave = tid >> 6;
    const int lane = tid & 63;
    const int wr = wave >> 2;          // 0..1  M half (128 rows)
    const int wc = wave & 3;           // 0..3  N strip (64 cols)

    const int rl = lane >> 2;          // staging: row within 16-row segment
    const int ps = lane & 3;           // staging: phys 16B slot
    const int fr = lane & 15;          // fragment row
    const int fq = lane >> 4;          // fragment k-chunk (16B unit)

    f32x4 acc[8][4] = {};

    // staging: wave w covers rows [w*32, w*32+32): 2 segments x 4 tensors
    // = 8 global_load_lds per wave per tile
    auto stage = [&](int buf, int k0) {
        bf16* base = smem + buf * SET_E;
        #pragma unroll
        for (int t = 0; t < 2; ++t) {
            int s = wave * 2 + t;                   // segment 0..15 (wave-uniform)
            int r = s * 16 + rl;                    // tile row
            int q = ps ^ (r & 3) ^ ((r >> 2) & 3);  // pre-swizzled global chunk
            size_t ga = (size_t)(m0 + r) * D_DIM + k0 + q * 8;
            size_t gb = (size_t)(n0 + r) * D_DIM + k0 + q * 8;
            bf16* dst = base + s * 512;             // wave-uniform; HW adds lane*16B
            gload_lds16(AH + ga, dst);
            gload_lds16(AL + ga, dst + TILE_E);
            gload_lds16(WH + gb, dst + 2 * TILE_E);
            gload_lds16(WL + gb, dst + 3 * TILE_E);
        }
    };

    // ---- prologue: tile 0 into buf 0
    stage(0, 0);

    #pragma unroll 1
    for (int kt = 0; kt < 32; ++kt) {
        const int cur = kt & 1;
        SCHED0;
        asm volatile("s_waitcnt vmcnt(0)" ::: "memory");   // stage(kt) landed
        SCHED0;
        __builtin_amdgcn_s_barrier();   // tile kt resident; reads(kt-1) consumed
        if (kt < 31)
            stage(cur ^ 1, (kt + 1) * 32);   // writes buf read at kt-1 — safe
        SCHED0;

        const bf16* tb = smem + cur * SET_E;
        bf16x8 wh[4], wl[4], ah[8], al[8];
        #pragma unroll
        for (int n = 0; n < 4; ++n) {
            int R = wc * 64 + n * 16 + fr;
            int p = fq ^ (R & 3) ^ ((R >> 2) & 3);
            int off = R * 32 + p * 8;
            wh[n] = *reinterpret_cast<const bf16x8*>(tb + 2 * TILE_E + off);
            wl[n] = *reinterpret_cast<const bf16x8*>(tb + 3 * TILE_E + off);
        }
        #pragma unroll
        for (int m = 0; m < 8; ++m) {
            int R = wr * 128 + m * 16 + fr;
            int p = fq ^ (R & 3) ^ ((R >> 2) & 3);
            int off = R * 32 + p * 8;
            ah[m] = *reinterpret_cast<const bf16x8*>(tb + off);
            al[m] = *reinterpret_cast<const bf16x8*>(tb + TILE_E + off);
        }

        __builtin_amdgcn_s_setprio(1);
        #pragma unroll
        for (int m = 0; m < 8; ++m)
            #pragma unroll
            for (int n = 0; n < 4; ++n) {
                acc[m][n] = __builtin_amdgcn_mfma_f32_16x16x32_bf16(ah[m], wh[n], acc[m][n], 0, 0, 0);
                acc[m][n] = __builtin_amdgcn_mfma_f32_16x16x32_bf16(ah[m], wl[n], acc[m][n], 0, 0, 0);
                acc[m][n] = __builtin_amdgcn_mfma_f32_16x16x32_bf16(al[m], wh[n], acc[m][n], 0, 0, 0);
            }
        __builtin_amdgcn_s_setprio(0);
    }

    // protect epilogue LDS-scratch reuse from any wave still reading buf1
    SCHED0;
    asm volatile("s_waitcnt lgkmcnt(0)" ::: "memory");
    SCHED0;
    __builtin_amdgcn_s_barrier();

    // ---- Epilogue via LDS transpose, 2 half-passes (per-wave 64x64 f32 =
    // 16 KiB x 8 waves = 128 KiB). Wave-private regions; DS in-order per wave.
    // C/D layout: col = lane&15 (=fr), row = (lane>>4)*4 + j.
    const int crow4 = (lane >> 4) * 4;
    float* cwave = reinterpret_cast<float*>(smem) + wave * 4096;
    const int rloc = lane >> 3;
    const int cloc = (lane & 7) * 8;

    #pragma unroll
    for (int half = 0; half < 2; ++half) {
        #pragma unroll
        for (int n = 0; n < 4; ++n) {
            const float bv = bias[n0 + wc * 64 + n * 16 + fr];
            const int lcol = n * 16 + fr;                 // local col 0..63
            const int chunk = lcol >> 2;
            #pragma unroll
            for (int mm = 0; mm < 4; ++mm) {
                const int m = half * 4 + mm;
                #pragma unroll
                for (int j = 0; j < 4; ++j) {
                    const int lrow = mm * 16 + crow4 + j; // local row 0..63
                    float v = acc[m][n][j] + bv;
                    if (MODE == 0) v = v > 0.f ? v : 0.f;
                    cwave[lrow * 64 + (chunk ^ (lrow & 15)) * 4 + (lcol & 3)] = v;
                }
            }
        }
        SCHED0;
        asm volatile("s_waitcnt lgkmcnt(0)" ::: "memory");
        SCHED0;

        #pragma unroll
        for (int pass = 0; pass < 8; ++pass) {
            const int lrow = pass * 8 + rloc;             // 0..63
            const int grow = m0 + wr * 128 + half * 64 + lrow;
            const size_t gbase = (size_t)grow * D_DIM + (n0 + wc * 64 + cloc);
            const int c0 = cloc >> 2;
            float4 v0 = *reinterpret_cast<const float4*>(&cwave[lrow * 64 + ((c0    ) ^ (lrow & 15)) * 4]);
            float4 v1 = *reinterpret_cast<const float4*>(&cwave[lrow * 64 + ((c0 + 1) ^ (lrow & 15)) * 4]);
            float vv[8] = {v0.x, v0.y, v0.z, v0.w, v1.x, v1.y, v1.z, v1.w};
            if (MODE != 0) {
                u16x8 rh = *reinterpret_cast<const u16x8*>(&RH[gbase]);
                u16x8 rl2 = *reinterpret_cast<const u16x8*>(&RL[gbase]);
                #pragma unroll
                for (int k = 0; k < 8; ++k)
                    vv[k] += bfbits2f(rh[k]) + bfbits2f(rl2[k]);
            }
            if (MODE == 2) {
                *reinterpret_cast<float4*>(&Of[gbase])     = make_float4(vv[0], vv[1], vv[2], vv[3]);
                *reinterpret_cast<float4*>(&Of[gbase + 4]) = make_float4(vv[4], vv[5], vv[6], vv[7]);
            } else {
                u16x8 ho, lo2;
                #pragma unroll
                for (int k = 0; k < 8; ++k) {
                    unsigned short h, l2;
                    split_bf(vv[k], h, l2);
                    ho[k] = h; lo2[k] = l2;
                }
                *reinterpret_cast<u16x8*>(&OH[gbase]) = ho;
                *reinterpret_cast<u16x8*>(&OL[gbase]) = lo2;
            }
        }
        SCHED0;
        asm volatile("s_waitcnt lgkmcnt(0)" ::: "memory");
        SCHED0;
    }
}

// ---------------------------------------------------------------------------
// LayerNorm on hi/lo pair. One block per row, 256 threads x 4 elems.
// ---------------------------------------------------------------------------
__global__ __launch_bounds__(256)
void ln_pair(const bf16* __restrict__ XH, const bf16* __restrict__ XL,
             bf16* __restrict__ YH, bf16* __restrict__ YL,
             const float* __restrict__ gamma, const float* __restrict__ beta)
{
    const int row = blockIdx.x;
    const int tid = threadIdx.x;
    const int lane = tid & 63;
    const int wave = tid >> 6;

    ushort4 uh = reinterpret_cast<const ushort4*>(XH + (size_t)row * D_DIM)[tid];
    ushort4 ul = reinterpret_cast<const ushort4*>(XL + (size_t)row * D_DIM)[tid];
    float v0 = bfbits2f(uh.x) + bfbits2f(ul.x);
    float v1 = bfbits2f(uh.y) + bfbits2f(ul.y);
    float v2 = bfbits2f(uh.z) + bfbits2f(ul.z);
    float v3 = bfbits2f(uh.w) + bfbits2f(ul.w);
    float s  = v0 + v1 + v2 + v3;
    float ss = v0 * v0 + v1 * v1 + v2 * v2 + v3 * v3;
    #pragma unroll
    for (int off = 32; off >= 1; off >>= 1) {
        s  += __shfl_xor(s, off, 64);
        ss += __shfl_xor(ss, off, 64);
    }
    __shared__ float red[8];
    if (lane == 0) { red[wave] = s; red[4 + wave] = ss; }
    __syncthreads();
    float S  = red[0] + red[1] + red[2] + red[3];
    float SS = red[4] + red[5] + red[6] + red[7];
    const float mean = S * (1.0f / D_DIM);
    const float var  = SS * (1.0f / D_DIM) - mean * mean;
    const float inv  = rsqrtf(var + 1e-5f);

    const int c0 = tid * 4;
    float y0 = (v0 - mean) * inv * gamma[c0 + 0] + beta[c0 + 0];
    float y1 = (v1 - mean) * inv * gamma[c0 + 1] + beta[c0 + 1];
    float y2 = (v2 - mean) * inv * gamma[c0 + 2] + beta[c0 + 2];
    float y3 = (v3 - mean) * inv * gamma[c0 + 3] + beta[c0 + 3];
    ushort4 oh, ol;
    split_bf(y0, oh.x, ol.x); split_bf(y1, oh.y, ol.y);
    split_bf(y2, oh.z, ol.z); split_bf(y3, oh.w, ol.w);
    reinterpret_cast<ushort4*>(YH + (size_t)row * D_DIM)[tid] = oh;
    reinterpret_cast<ushort4*>(YL + (size_t)row * D_DIM)[tid] = ol;
}

// ---------------------------------------------------------------------------
extern "C" void kernel_launch(void* const* d_in, const int* in_sizes, int n_in,
                              void* d_out, int out_size, void* d_ws, size_t ws_size,
                              hipStream_t stream)
{
    const float* x      = (const float*)d_in[0];
    const int*   wq     = (const int*)d_in[1];
    const float* scales = (const float*)d_in[2];
    const float* bias   = (const float*)d_in[3];
    const float* lora_a = (const float*)d_in[4];
    const float* lora_b = (const float*)d_in[5];
    const float* ln_g   = (const float*)d_in[6];
    const float* ln_b   = (const float*)d_in[7];
    float* out = (float*)d_out;

    char* ws = (char*)d_ws;
    const size_t W_ELEMS = (size_t)NLAYER * D_DIM * D_DIM;
    const size_t H_ELEMS = (size_t)B_ROWS * D_DIM;
    bf16* WHp = (bf16*)ws;
    bf16* WLp = WHp + W_ELEMS;
    bf16* HAh = WLp + W_ELEMS;
    bf16* HAl = HAh + H_ELEMS;
    bf16* HBh = HAl + H_ELEMS;
    bf16* HBl = HBh + H_ELEMS;
    // third activation pair lives in d_out (dead before final write)
    bf16* HCh = (bf16*)d_out;
    bf16* HCl = HCh + H_ELEMS;

    build_weff<<<dim3(NLAYER * 128), dim3(256), 0, stream>>>(wq, scales, lora_a, lora_b, WHp, WLp);
    cast_split<<<dim3((B_ROWS * D_DIM) / (256 * 4)), dim3(256), 0, stream>>>(x, HAh, HAl);

    dim3 ggrid(256);  // 64 m-tiles x 4 n-tiles, swizzled in-kernel
    for (int j = 0; j < 6; ++j) {
        const int l0 = 3 * j;
        const bf16* WH0 = WHp + (size_t)l0 * D_DIM * D_DIM;
        const bf16* WL0 = WLp + (size_t)l0 * D_DIM * D_DIM;
        const bf16* WH1 = WHp + (size_t)(l0 + 1) * D_DIM * D_DIM;
        const bf16* WL1 = WLp + (size_t)(l0 + 1) * D_DIM * D_DIM;
        const bf16* WH2 = WHp + (size_t)(l0 + 2) * D_DIM * D_DIM;
        const bf16* WL2 = WLp + (size_t)(l0 + 2) * D_DIM * D_DIM;
        const float* b0 = bias + (size_t)l0 * D_DIM;
        const float* b1 = bias + (size_t)(l0 + 1) * D_DIM;
        const float* b2 = bias + (size_t)(l0 + 2) * D_DIM;
        if (j < 5) {
            qgemm3<0><<<ggrid, 512, 0, stream>>>(HAh, HAl, WH0, WL0, b0, nullptr, nullptr, HBh, HBl, nullptr);
            qgemm3<0><<<ggrid, 512, 0, stream>>>(HBh, HBl, WH1, WL1, b1, nullptr, nullptr, HCh, HCl, nullptr);
            qgemm3<1><<<ggrid, 512, 0, stream>>>(HCh, HCl, WH2, WL2, b2, HAh, HAl, HBh, HBl, nullptr);
            ln_pair<<<dim3(B_ROWS), dim3(256), 0, stream>>>(HBh, HBl, HAh, HAl,
                                                            ln_g + (size_t)j * D_DIM, ln_b + (size_t)j * D_DIM);
        } else {
            qgemm3<0><<<ggrid, 512, 0, stream>>>(HAh, HAl, WH0, WL0, b0, nullptr, nullptr, HCh, HCl, nullptr);
            qgemm3<0><<<ggrid, 512, 0, stream>>>(HCh, HCl, WH1, WL1, b1, nullptr, nullptr, HBh, HBl, nullptr);
            qgemm3<2><<<ggrid, 512, 0, stream>>>(HBh, HBl, WH2, WL2, b2, HAh, HAl, nullptr, nullptr, out);
        }
    }
}